// Round 13
// baseline (1691.887 us; speedup 1.0000x reference)
//
#include <hip/hip_runtime.h>
#include <stdint.h>

#define NTHR 256
#define PP   28              // patches per block (252 conv1 tasks <= 256 threads)
#define HST  104             // H row stride in bf16 elems
#define WST  104             // W2b row stride in bf16 elems
#define OCT  8               // channels per octet (8 H buffers, 2 barriers per octet)
#define HBUF (32*HST)        // u16 elems per channel H buffer (6656 B)
#define NPATCH 32768
#define W2B_ELEMS (64*128*WST)   // 851,968 u16 = 1,703,936 B in d_ws
#define HW (384*384)

typedef __attribute__((ext_vector_type(8))) short bf16x8;
typedef __attribute__((ext_vector_type(4))) float f32x4;
typedef uint32_t u32;
typedef uint16_t u16;

__device__ __forceinline__ u16 f2bf(float f){
    u32 x = __float_as_uint(f);
    return (u16)((x + 0x7fffu + ((x >> 16) & 1u)) >> 16);
}
__device__ __forceinline__ u32 pack2(float a, float b){
    return (u32)f2bf(a) | ((u32)f2bf(b) << 16);
}
__device__ __forceinline__ bf16x8 u4bf(uint4 x){
    union { uint4 u; bf16x8 b; } c; c.u = x; return c.b;
}

// ---- prep: W2 fp32 [128][64][81] -> bf16 d_ws [64 g][128 oc][104], zeros in [81,104) ----
__global__ void w2_prep(const float* __restrict__ W2, u16* __restrict__ W2b){
    int i = blockIdx.x * 256 + threadIdx.x;
    if (i >= W2B_ELEMS) return;
    int g   = i / (128 * WST);
    int rem = i - g * (128 * WST);
    int oc  = rem / WST;
    int k   = rem - oc * WST;
    u16 v = 0;
    if (k < 81) v = f2bf(W2[(size_t)oc * 5184 + g * 81 + k]);
    W2b[i] = v;
}

// load B fragments for channel g into registers (bypasses LDS entirely)
template<bool USEWS>
__device__ __forceinline__ void load_B(const u16* __restrict__ W2b,
                                       const float* __restrict__ W2,
                                       int g, int oc0, int oc1, int g4,
                                       uint4 (&PB)[3][2])
{
    if constexpr (USEWS) {
        const u16* base = W2b + (size_t)g * (128 * WST);
        #pragma unroll
        for (int s = 0; s < 3; ++s) {
            const int ko = s * 32 + g4 * 8;
            PB[s][0] = *(const uint4*)(base + oc0 * WST + ko);
            PB[s][1] = *(const uint4*)(base + oc1 * WST + ko);
        }
    } else {
        #pragma unroll
        for (int s = 0; s < 3; ++s) {
            const int ko = s * 32 + g4 * 8;
            #pragma unroll
            for (int half = 0; half < 2; ++half) {
                const float* so = W2 + (size_t)(half ? oc1 : oc0) * 5184 + g * 81;
                u32 q0 = pack2(ko     < 81 ? so[ko]     : 0.f, ko + 1 < 81 ? so[ko + 1] : 0.f);
                u32 q1 = pack2(ko + 2 < 81 ? so[ko + 2] : 0.f, ko + 3 < 81 ? so[ko + 3] : 0.f);
                u32 q2 = pack2(ko + 4 < 81 ? so[ko + 4] : 0.f, ko + 5 < 81 ? so[ko + 5] : 0.f);
                u32 q3 = pack2(ko + 6 < 81 ? so[ko + 6] : 0.f, ko + 7 < 81 ? so[ko + 7] : 0.f);
                PB[s][half] = (uint4){q0, q1, q2, q3};
            }
        }
    }
}

// 3 MFMA K-steps for one channel: A from LDS buffer, B from registers
__device__ __forceinline__ void mfma_ch(const u16* __restrict__ Hb, int n16, int g4,
                                        const uint4 (&PB)[3][2], f32x4 (&acc)[2][2])
{
    #pragma unroll
    for (int s = 0; s < 3; ++s) {
        const int ko = s * 32 + g4 * 8;
        bf16x8 a0  = *(const bf16x8*)(Hb + (n16     ) * HST + ko);
        bf16x8 a1  = *(const bf16x8*)(Hb + (16 + n16) * HST + ko);
        bf16x8 vb0 = u4bf(PB[s][0]);
        bf16x8 vb1 = u4bf(PB[s][1]);
        acc[0][0] = __builtin_amdgcn_mfma_f32_16x16x32_bf16(a0, vb0, acc[0][0], 0, 0, 0);
        acc[0][1] = __builtin_amdgcn_mfma_f32_16x16x32_bf16(a0, vb1, acc[0][1], 0, 0, 0);
        acc[1][0] = __builtin_amdgcn_mfma_f32_16x16x32_bf16(a1, vb0, acc[1][0], 0, 0, 0);
        acc[1][1] = __builtin_amdgcn_mfma_f32_16x16x32_bf16(a1, vb1, acc[1][1], 0, 0, 0);
    }
}

template<bool USEWS>
__global__ __launch_bounds__(NTHR, 3)
void patch_embed(const float* __restrict__ images,
                 const float* __restrict__ coords,
                 const int*   __restrict__ t_src,
                 const float* __restrict__ W1,
                 const float* __restrict__ b1,
                 const float* __restrict__ W2,
                 const u16*   __restrict__ W2b,
                 const float* __restrict__ b2,
                 float* __restrict__ out)
{
    __shared__ __align__(16) u16 Hl[OCT * HBUF];     // 53248 B: 8 channel buffers
    __shared__ int poff[PP];                         // total ~53.4 KB -> 3 blk/CU

    const int tid  = threadIdx.x;
    const int blk  = blockIdx.x;
    const int lane = tid & 63;
    const int w    = tid >> 6;
    const int n16  = lane & 15;
    const int g4   = lane >> 4;

    // per-patch source offsets (round-half-even like jnp.round)
    if (tid < PP) {
        int gp = blk * PP + tid;
        if (gp >= NPATCH) gp = NPATCH - 1;           // tail block: valid dummy
        int b = gp >> 11;
        int n = gp & 2047;
        float cx = coords[(size_t)(b * 2048 + n) * 2 + 0];
        float cy = coords[(size_t)(b * 2048 + n) * 2 + 1];
        int u = (int)rintf(cx * 384.0f);
        int v = (int)rintf(cy * 384.0f);
        u = min(max(u, 4), 379);
        v = min(max(v, 4), 379);
        int t = t_src[b * 2048 + n];
        t = min(max(t, 0), 15);
        poff[tid] = ((b * 16 + t) * 3) * HW + (v - 4) * 384 + (u - 4);
    }
    // zero all 8 H buffers once (rows 28..31 and k in [81,104) stay zero forever;
    // conv1 rewrites k in [0,81) of rows 0..27 every octet)
    {
        u32* Hz = (u32*)Hl;
        for (int j = tid; j < OCT * HBUF / 2; j += NTHR) Hz[j] = 0u;
    }
    __syncthreads();

    // fixed conv1 task: (p0, y0). Load 3 rows x 27 floats DIRECTLY global -> registers.
    const bool has = tid < PP * 9;                    // 252 tasks
    const int p0 = has ? tid / 9 : 0;
    const int y0 = has ? tid - 9 * (tid / 9) : 0;
    float rf[3][27];
    {
        const int base = poff[p0];
        #pragma unroll
        for (int dy = 0; dy < 3; ++dy) {
            const int yy = y0 - 1 + dy;               // real image row within patch
            const bool vrow = has && (yy >= 0) && (yy <= 8);
            #pragma unroll
            for (int j = 0; j < 27; ++j) rf[dy][j] = 0.f;
            if (vrow) {
                #pragma unroll
                for (int c = 0; c < 3; ++c) {
                    const float* rp = images + (size_t)base + c * HW + yy * 384;
                    #pragma unroll
                    for (int x = 0; x < 9; ++x) rf[dy][c * 9 + x] = rp[x];
                }
            }
        }
    }

    const int oc0 = w * 32 + n16;
    const int oc1 = oc0 + 16;

    // B prefetch for channel 0 (two alternating named register sets)
    uint4 PBa[3][2], PBb[3][2];
    load_B<USEWS>(W2b, W2, 0, oc0, oc1, g4, PBa);

    f32x4 acc[2][2];
    #pragma unroll
    for (int mt = 0; mt < 2; ++mt)
        #pragma unroll
        for (int nt = 0; nt < 2; ++nt) acc[mt][nt] = (f32x4){0.f, 0.f, 0.f, 0.f};

    #pragma unroll 1
    for (int o = 0; o < 64 / OCT; ++o) {
        // ---- phase 1: conv1 for channels o*8 .. o*8+7 into Hl[0..7] ----
        #pragma unroll 2
        for (int i = 0; i < OCT; ++i) {
            const int c = o * OCT + i;
            const float* W1c = W1 + (size_t)c * 27;
            const float bias = b1[c];
            float a[9];
            #pragma unroll
            for (int x = 0; x < 9; ++x) a[x] = bias;
            #pragma unroll
            for (int dy = 0; dy < 3; ++dy) {
                #pragma unroll
                for (int cc = 0; cc < 3; ++cc) {
                    const float* rr = rf[dy] + cc * 9;
                    const int wi = cc * 9 + dy * 3;
                    const float w0 = W1c[wi], w1 = W1c[wi + 1], w2 = W1c[wi + 2];
                    #pragma unroll
                    for (int xo = 0; xo < 9; ++xo) {
                        a[xo] = fmaf(rr[xo], w1, a[xo]);
                        if (xo >= 1) a[xo] = fmaf(rr[xo - 1], w0, a[xo]);
                        if (xo <= 7) a[xo] = fmaf(rr[xo + 1], w2, a[xo]);
                    }
                }
            }
            if (has) {
                u16* Hb = Hl + i * HBUF + p0 * HST + y0 * 9;
                #pragma unroll
                for (int xo = 0; xo < 9; ++xo) {
                    float v = a[xo] > 0.f ? a[xo] : 0.f;   // ReLU
                    Hb[xo] = f2bf(v);
                }
            }
        }

        __syncthreads();   // all H(octet) visible; also protects prior-octet reads

        // ---- phase 2: 8 channels of MFMA, B software-pipelined in registers ----
        #pragma unroll
        for (int i = 0; i < OCT; i += 2) {
            const int c = o * OCT + i;
            load_B<USEWS>(W2b, W2, c + 1, oc0, oc1, g4, PBb);     // B(c+1)
            mfma_ch(Hl + i * HBUF, n16, g4, PBa, acc);            // uses B(c)
            const int cn = (i < OCT - 2) ? (c + 2)
                         : ((o < 64 / OCT - 1) ? (o + 1) * OCT : 0);  // next octet ch (or dummy)
            load_B<USEWS>(W2b, W2, cn, oc0, oc1, g4, PBa);        // B(next)
            mfma_ch(Hl + (i + 1) * HBUF, n16, g4, PBb, acc);      // uses B(c+1)
        }

        __syncthreads();   // protect H buffers before next octet's conv1 stores
    }

    // ---- epilogue: + b2, write fp32 (B,N,128), guard tail rows ----
    const float bias0 = b2[oc0];
    const float bias1 = b2[oc1];
    #pragma unroll
    for (int mt = 0; mt < 2; ++mt) {
        #pragma unroll
        for (int r = 0; r < 4; ++r) {
            int p = mt * 16 + g4 * 4 + r;
            int gp = blk * PP + p;
            if (p < PP && gp < NPATCH) {
                size_t rowo = (size_t)gp * 128;
                out[rowo + oc0] = acc[mt][0][r] + bias0;
                out[rowo + oc1] = acc[mt][1][r] + bias1;
            }
        }
    }
}

extern "C" void kernel_launch(void* const* d_in, const int* in_sizes, int n_in,
                              void* d_out, int out_size, void* d_ws, size_t ws_size,
                              hipStream_t stream)
{
    const float* images = (const float*)d_in[0];
    const float* coords = (const float*)d_in[1];
    const int*   t_src  = (const int*)d_in[2];
    const float* W1     = (const float*)d_in[3];
    const float* b1     = (const float*)d_in[4];
    const float* W2     = (const float*)d_in[5];
    const float* b2     = (const float*)d_in[6];
    float* out = (float*)d_out;
    u16* W2b = (u16*)d_ws;

    const int grid = (NPATCH + PP - 1) / PP;   // 1171
    const bool usews = ws_size >= (size_t)W2B_ELEMS * sizeof(u16);   // 1.70 MB

    if (usews) {
        hipLaunchKernelGGL(w2_prep, dim3((W2B_ELEMS + 255) / 256), dim3(256), 0, stream,
                           W2, W2b);
        hipLaunchKernelGGL(patch_embed<true>, dim3(grid), dim3(NTHR), 0, stream,
                           images, coords, t_src, W1, b1, W2, W2b, b2, out);
    } else {
        hipLaunchKernelGGL(patch_embed<false>, dim3(grid), dim3(NTHR), 0, stream,
                           images, coords, t_src, W1, b1, W2, W2b, b2, out);
    }
}

// Round 14
// 270.782 us; speedup vs baseline: 6.2482x; 6.2482x over previous
//
#include <hip/hip_runtime.h>
#include <stdint.h>

#define NTHR 256
#define PP   28              // patches per block (252 conv1 tasks <= 256 threads)
#define HST  104             // H row stride in bf16 elems
#define WST  104             // W2b row stride in bf16 elems
#define NPATCH 32768
#define CHALF 32             // channels per block (64 split across 2 blocks)
#define W2B_ELEMS (64*128*WST)   // 851,968 u16 = 1,703,936 B in d_ws
#define HW (384*384)

typedef __attribute__((ext_vector_type(8))) short bf16x8;
typedef __attribute__((ext_vector_type(4))) float f32x4;
typedef uint32_t u32;
typedef uint16_t u16;

__device__ __forceinline__ u16 f2bf(float f){
    u32 x = __float_as_uint(f);
    return (u16)((x + 0x7fffu + ((x >> 16) & 1u)) >> 16);
}
__device__ __forceinline__ u32 pack2(float a, float b){
    return (u32)f2bf(a) | ((u32)f2bf(b) << 16);
}
__device__ __forceinline__ bf16x8 u4bf(uint4 x){
    union { uint4 u; bf16x8 b; } c; c.u = x; return c.b;
}

// ---- prep: W2 fp32 [128][64][81] -> bf16 d_ws [64 g][128 oc][104], zeros in [81,104) ----
__global__ void w2_prep(const float* __restrict__ W2, u16* __restrict__ W2b){
    int i = blockIdx.x * 256 + threadIdx.x;
    if (i >= W2B_ELEMS) return;
    int g   = i / (128 * WST);
    int rem = i - g * (128 * WST);
    int oc  = rem / WST;
    int k   = rem - oc * WST;
    u16 v = 0;
    if (k < 81) v = f2bf(W2[(size_t)oc * 5184 + g * 81 + k]);
    W2b[i] = v;
}

// load B fragments for channel g into registers (bypasses LDS entirely)
template<bool USEWS>
__device__ __forceinline__ void load_B(const u16* __restrict__ W2b,
                                       const float* __restrict__ W2,
                                       int g, int oc0, int oc1, int g4,
                                       uint4 (&PB)[3][2])
{
    if constexpr (USEWS) {
        const u16* base = W2b + (size_t)g * (128 * WST);
        #pragma unroll
        for (int s = 0; s < 3; ++s) {
            const int ko = s * 32 + g4 * 8;
            PB[s][0] = *(const uint4*)(base + oc0 * WST + ko);
            PB[s][1] = *(const uint4*)(base + oc1 * WST + ko);
        }
    } else {
        #pragma unroll
        for (int s = 0; s < 3; ++s) {
            const int ko = s * 32 + g4 * 8;
            #pragma unroll
            for (int half = 0; half < 2; ++half) {
                const float* so = W2 + (size_t)(half ? oc1 : oc0) * 5184 + g * 81;
                u32 q0 = pack2(ko     < 81 ? so[ko]     : 0.f, ko + 1 < 81 ? so[ko + 1] : 0.f);
                u32 q1 = pack2(ko + 2 < 81 ? so[ko + 2] : 0.f, ko + 3 < 81 ? so[ko + 3] : 0.f);
                u32 q2 = pack2(ko + 4 < 81 ? so[ko + 4] : 0.f, ko + 5 < 81 ? so[ko + 5] : 0.f);
                u32 q3 = pack2(ko + 6 < 81 ? so[ko + 6] : 0.f, ko + 7 < 81 ? so[ko + 7] : 0.f);
                PB[s][half] = (uint4){q0, q1, q2, q3};
            }
        }
    }
}

template<bool USEWS>
__global__ __launch_bounds__(NTHR)
void patch_embed(const float* __restrict__ images,
                 const float* __restrict__ coords,
                 const int*   __restrict__ t_src,
                 const float* __restrict__ W1,
                 const float* __restrict__ b1,
                 const float* __restrict__ W2,
                 const u16*   __restrict__ W2b,
                 const float* __restrict__ b2,
                 float* __restrict__ out)
{
    __shared__ __align__(16) u16 Hl[2][32 * HST];    // 13312 B double-buffered H
    __shared__ int poff[PP];                         // total ~13.4 KB LDS

    const int tid  = threadIdx.x;
    const int pb   = blockIdx.x >> 1;                // patch-group id
    const int half = blockIdx.x & 1;                 // channel half
    const int hbase = half * CHALF;
    const int lane = tid & 63;
    const int w    = tid >> 6;
    const int n16  = lane & 15;
    const int g4   = lane >> 4;

    // per-patch source offsets (round-half-even like jnp.round)
    if (tid < PP) {
        int gp = pb * PP + tid;
        if (gp >= NPATCH) gp = NPATCH - 1;           // tail block: valid dummy
        int b = gp >> 11;
        int n = gp & 2047;
        float cx = coords[(size_t)(b * 2048 + n) * 2 + 0];
        float cy = coords[(size_t)(b * 2048 + n) * 2 + 1];
        int u = (int)rintf(cx * 384.0f);
        int v = (int)rintf(cy * 384.0f);
        u = min(max(u, 4), 379);
        v = min(max(v, 4), 379);
        int t = t_src[b * 2048 + n];
        t = min(max(t, 0), 15);
        poff[tid] = ((b * 16 + t) * 3) * HW + (v - 4) * 384 + (u - 4);
    }
    // zero both H buffers once (rows 28..31 and k in [81,104) stay zero forever)
    {
        u32* Hz = (u32*)Hl;
        #pragma unroll
        for (int j = 0; j < 13; ++j) Hz[tid + j * NTHR] = 0u;   // 2*32*52 = 3328 u32
    }
    __syncthreads();

    // fixed conv1 task: (p0, y0). Load 3 rows x 27 floats DIRECTLY global -> registers.
    const bool has = tid < PP * 9;                    // 252 tasks
    const int p0 = has ? tid / 9 : 0;
    const int y0 = has ? tid - 9 * (tid / 9) : 0;
    float rf[3][27];
    {
        const int base = poff[p0];
        #pragma unroll
        for (int dy = 0; dy < 3; ++dy) {
            const int yy = y0 - 1 + dy;               // real image row within patch
            const bool vrow = has && (yy >= 0) && (yy <= 8);
            #pragma unroll
            for (int j = 0; j < 27; ++j) rf[dy][j] = 0.f;
            if (vrow) {
                #pragma unroll
                for (int c = 0; c < 3; ++c) {
                    const float* rp = images + (size_t)base + c * HW + yy * 384;
                    #pragma unroll
                    for (int x = 0; x < 9; ++x) rf[dy][c * 9 + x] = rp[x];
                }
            }
        }
    }

    // B-fragment register prefetch for first channel of this half
    const int oc0 = w * 32 + n16;
    const int oc1 = oc0 + 16;
    uint4 PB[3][2];
    load_B<USEWS>(W2b, W2, hbase, oc0, oc1, g4, PB);

    f32x4 acc[2][2];
    #pragma unroll
    for (int mt = 0; mt < 2; ++mt)
        #pragma unroll
        for (int nt = 0; nt < 2; ++nt) acc[mt][nt] = (f32x4){0.f, 0.f, 0.f, 0.f};

    #pragma unroll 1
    for (int g = 0; g < CHALF; ++g) {
        const int c = hbase + g;
        // ---- conv1 for channel c: pure register FMAs ----
        const float* W1c = W1 + (size_t)c * 27;
        const float bias = b1[c];
        u16 h9[9];
        {
            float a[9];
            #pragma unroll
            for (int x = 0; x < 9; ++x) a[x] = bias;
            #pragma unroll
            for (int dy = 0; dy < 3; ++dy) {
                #pragma unroll
                for (int cc = 0; cc < 3; ++cc) {
                    const float* rr = rf[dy] + cc * 9;
                    const int wi = cc * 9 + dy * 3;
                    const float w0 = W1c[wi], w1 = W1c[wi + 1], w2 = W1c[wi + 2];
                    #pragma unroll
                    for (int xo = 0; xo < 9; ++xo) {
                        a[xo] = fmaf(rr[xo], w1, a[xo]);
                        if (xo >= 1) a[xo] = fmaf(rr[xo - 1], w0, a[xo]);
                        if (xo <= 7) a[xo] = fmaf(rr[xo + 1], w2, a[xo]);
                    }
                }
            }
            #pragma unroll
            for (int xo = 0; xo < 9; ++xo) {
                float v = a[xo] > 0.f ? a[xo] : 0.f;   // ReLU
                h9[xo] = f2bf(v);
            }
        }

        // H stores into buffer g&1 (k = y0*9+xo in [0,81))
        {
            u16* Hb = &Hl[g & 1][0];
            if (has) {
                #pragma unroll
                for (int xo = 0; xo < 9; ++xo) Hb[p0 * HST + y0 * 9 + xo] = h9[xo];
            }
        }

        __syncthreads();   // Hl(g) visible; MFMA(g-1) reads of buf[(g-1)&1] all done

        // ---- conv2 partial: 3 MFMA K-steps, A from LDS buf, B from registers ----
        {
            const u16* Hb = &Hl[g & 1][0];
            #pragma unroll
            for (int s = 0; s < 3; ++s) {
                const int ko = s * 32 + g4 * 8;
                bf16x8 a0  = *(const bf16x8*)(Hb + (n16     ) * HST + ko);
                bf16x8 a1  = *(const bf16x8*)(Hb + (16 + n16) * HST + ko);
                bf16x8 vb0 = u4bf(PB[s][0]);
                bf16x8 vb1 = u4bf(PB[s][1]);
                acc[0][0] = __builtin_amdgcn_mfma_f32_16x16x32_bf16(a0, vb0, acc[0][0], 0, 0, 0);
                acc[0][1] = __builtin_amdgcn_mfma_f32_16x16x32_bf16(a0, vb1, acc[0][1], 0, 0, 0);
                acc[1][0] = __builtin_amdgcn_mfma_f32_16x16x32_bf16(a1, vb0, acc[1][0], 0, 0, 0);
                acc[1][1] = __builtin_amdgcn_mfma_f32_16x16x32_bf16(a1, vb1, acc[1][1], 0, 0, 0);
            }
        }

        // reload PB for next channel (WAR-safe after MFMA issue; hides under conv1)
        if (g < CHALF - 1) load_B<USEWS>(W2b, W2, c + 1, oc0, oc1, g4, PB);
    }

    // ---- epilogue: atomicAdd halves into zeroed out; half 0 contributes b2 ----
    const float bias0 = half == 0 ? b2[oc0] : 0.f;
    const float bias1 = half == 0 ? b2[oc1] : 0.f;
    #pragma unroll
    for (int mt = 0; mt < 2; ++mt) {
        #pragma unroll
        for (int r = 0; r < 4; ++r) {
            int p = mt * 16 + g4 * 4 + r;
            int gp = pb * PP + p;
            if (p < PP && gp < NPATCH) {
                size_t rowo = (size_t)gp * 128;
                atomicAdd(out + rowo + oc0, acc[mt][0][r] + bias0);
                atomicAdd(out + rowo + oc1, acc[mt][1][r] + bias1);
            }
        }
    }
}

extern "C" void kernel_launch(void* const* d_in, const int* in_sizes, int n_in,
                              void* d_out, int out_size, void* d_ws, size_t ws_size,
                              hipStream_t stream)
{
    const float* images = (const float*)d_in[0];
    const float* coords = (const float*)d_in[1];
    const int*   t_src  = (const int*)d_in[2];
    const float* W1     = (const float*)d_in[3];
    const float* b1     = (const float*)d_in[4];
    const float* W2     = (const float*)d_in[5];
    const float* b2     = (const float*)d_in[6];
    float* out = (float*)d_out;
    u16* W2b = (u16*)d_ws;

    // zero the output (atomic accumulation; harness does not re-zero between replays)
    hipMemsetAsync(out, 0, (size_t)out_size * sizeof(float), stream);

    const int grid = 2 * ((NPATCH + PP - 1) / PP);   // 2342: (patch-group, channel-half)
    const bool usews = ws_size >= (size_t)W2B_ELEMS * sizeof(u16);   // 1.70 MB

    if (usews) {
        hipLaunchKernelGGL(w2_prep, dim3((W2B_ELEMS + 255) / 256), dim3(256), 0, stream,
                           W2, W2b);
        hipLaunchKernelGGL(patch_embed<true>, dim3(grid), dim3(NTHR), 0, stream,
                           images, coords, t_src, W1, b1, W2, W2b, b2, out);
    } else {
        hipLaunchKernelGGL(patch_embed<false>, dim3(grid), dim3(NTHR), 0, stream,
                           images, coords, t_src, W1, b1, W2, W2b, b2, out);
    }
}

// Round 15
// 225.930 us; speedup vs baseline: 7.4885x; 1.1985x over previous
//
#include <hip/hip_runtime.h>
#include <stdint.h>

#define NTHR 256
#define PP   28              // patches per block (252 conv1 tasks <= 256 threads)
#define HST  104             // H row stride in bf16 elems (K=96 + 8 pad)
#define WST  104             // W2b row stride in bf16 elems
#define HBUF (32*HST)        // u16 elems per channel H buffer (6656 B)
#define NPATCH 32768
#define W2B_ELEMS (64*128*WST)   // 851,968 u16 = 1,703,936 B in d_ws
#define HW (384*384)

typedef __attribute__((ext_vector_type(8))) short bf16x8;
typedef __attribute__((ext_vector_type(4))) float f32x4;
typedef uint32_t u32;
typedef uint16_t u16;

__device__ __forceinline__ u16 f2bf(float f){
    u32 x = __float_as_uint(f);
    return (u16)((x + 0x7fffu + ((x >> 16) & 1u)) >> 16);
}
__device__ __forceinline__ u32 pack2(float a, float b){
    return (u32)f2bf(a) | ((u32)f2bf(b) << 16);
}
__device__ __forceinline__ bf16x8 u4bf(uint4 x){
    union { uint4 u; bf16x8 b; } c; c.u = x; return c.b;
}
// packed fp32x2 -> bf16x2 (RNE), single instruction
__device__ __forceinline__ u32 cvtpk(float lo, float hi){
    u32 r;
    asm("v_cvt_pk_bf16_f32 %0, %1, %2" : "=v"(r) : "v"(lo), "v"(hi));
    return r;
}

// ---- prep: W2 fp32 [128][64][81] -> bf16 d_ws [64 g][128 oc][104] with k = y*10+x
//      (x=9 column and k in [90,104) are zero) ----
__global__ void w2_prep(const float* __restrict__ W2, u16* __restrict__ W2b){
    int i = blockIdx.x * 256 + threadIdx.x;
    if (i >= W2B_ELEMS) return;
    int g   = i / (128 * WST);
    int rem = i - g * (128 * WST);
    int oc  = rem / WST;
    int k   = rem - oc * WST;
    int y   = k / 10;
    int x   = k - y * 10;
    u16 v = 0;
    if (y < 9 && x < 9) v = f2bf(W2[(size_t)oc * 5184 + g * 81 + y * 9 + x]);
    W2b[i] = v;
}

// load B fragments for channel g into registers (bypasses LDS entirely)
template<bool USEWS>
__device__ __forceinline__ void load_B(const u16* __restrict__ W2b,
                                       const float* __restrict__ W2,
                                       int g, int oc0, int oc1, int g4,
                                       uint4 (&PB)[3][2])
{
    if constexpr (USEWS) {
        const u16* base = W2b + (size_t)g * (128 * WST);
        #pragma unroll
        for (int s = 0; s < 3; ++s) {
            const int ko = s * 32 + g4 * 8;
            PB[s][0] = *(const uint4*)(base + oc0 * WST + ko);
            PB[s][1] = *(const uint4*)(base + oc1 * WST + ko);
        }
    } else {
        #pragma unroll
        for (int s = 0; s < 3; ++s) {
            const int ko = s * 32 + g4 * 8;
            #pragma unroll
            for (int half = 0; half < 2; ++half) {
                const float* so = W2 + (size_t)(half ? oc1 : oc0) * 5184 + g * 81;
                float v[8];
                #pragma unroll
                for (int j = 0; j < 8; ++j) {
                    int k = ko + j;
                    int y = k / 10, x = k - y * 10;
                    v[j] = (y < 9 && x < 9) ? so[y * 9 + x] : 0.f;
                }
                PB[s][half] = (uint4){pack2(v[0], v[1]), pack2(v[2], v[3]),
                                      pack2(v[4], v[5]), pack2(v[6], v[7])};
            }
        }
    }
}

// 3 MFMA K-steps for one channel: A from LDS buffer, B from registers
__device__ __forceinline__ void mfma_ch(const u16* __restrict__ Hb, int n16, int g4,
                                        const uint4 (&PB)[3][2], f32x4 (&acc)[2][2])
{
    #pragma unroll
    for (int s = 0; s < 3; ++s) {
        const int ko = s * 32 + g4 * 8;
        bf16x8 a0  = *(const bf16x8*)(Hb + (n16     ) * HST + ko);
        bf16x8 a1  = *(const bf16x8*)(Hb + (16 + n16) * HST + ko);
        bf16x8 vb0 = u4bf(PB[s][0]);
        bf16x8 vb1 = u4bf(PB[s][1]);
        acc[0][0] = __builtin_amdgcn_mfma_f32_16x16x32_bf16(a0, vb0, acc[0][0], 0, 0, 0);
        acc[0][1] = __builtin_amdgcn_mfma_f32_16x16x32_bf16(a0, vb1, acc[0][1], 0, 0, 0);
        acc[1][0] = __builtin_amdgcn_mfma_f32_16x16x32_bf16(a1, vb0, acc[1][0], 0, 0, 0);
        acc[1][1] = __builtin_amdgcn_mfma_f32_16x16x32_bf16(a1, vb1, acc[1][1], 0, 0, 0);
    }
}

template<bool USEWS>
__global__ __launch_bounds__(NTHR, 2)
void patch_embed(const float* __restrict__ images,
                 const float* __restrict__ coords,
                 const int*   __restrict__ t_src,
                 const float* __restrict__ W1,
                 const float* __restrict__ b1,
                 const float* __restrict__ W2,
                 const u16*   __restrict__ W2b,
                 const float* __restrict__ b2,
                 float* __restrict__ out)
{
    __shared__ __align__(16) u16 Hl[8][HBUF];        // 53248 B: 2 dbuf x 4 channels
    __shared__ int poff[PP];                         // total ~53.4 KB -> 3 blk/CU

    const int tid  = threadIdx.x;
    const int blk  = blockIdx.x;
    const int lane = tid & 63;
    const int w    = tid >> 6;
    const int n16  = lane & 15;
    const int g4   = lane >> 4;

    // per-patch source offsets (round-half-even like jnp.round)
    if (tid < PP) {
        int gp = blk * PP + tid;
        if (gp >= NPATCH) gp = NPATCH - 1;           // tail block: valid dummy
        int b = gp >> 11;
        int n = gp & 2047;
        float cx = coords[(size_t)(b * 2048 + n) * 2 + 0];
        float cy = coords[(size_t)(b * 2048 + n) * 2 + 1];
        int u = (int)rintf(cx * 384.0f);
        int v = (int)rintf(cy * 384.0f);
        u = min(max(u, 4), 379);
        v = min(max(v, 4), 379);
        int t = t_src[b * 2048 + n];
        t = min(max(t, 0), 15);
        poff[tid] = ((b * 16 + t) * 3) * HW + (v - 4) * 384 + (u - 4);
    }
    // zero all 8 H buffers once (rows 28..31, k in [90,104) stay zero forever;
    // conv1 rewrites k in [0,90) of rows 0..27 every pass)
    {
        u32* Hz = (u32*)Hl;
        #pragma unroll
        for (int j = 0; j < 52; ++j) Hz[tid + j * NTHR] = 0u;   // 8*32*52 = 13312 u32
    }
    __syncthreads();

    // fixed conv1 task: (p0, y0). Load 3 rows x 27 floats DIRECTLY global -> registers.
    const bool has = tid < PP * 9;                    // 252 tasks
    const int p0 = has ? tid / 9 : 0;
    const int y0 = has ? tid - 9 * (tid / 9) : 0;
    float rf[3][27];
    {
        const int base = poff[p0];
        #pragma unroll
        for (int dy = 0; dy < 3; ++dy) {
            const int yy = y0 - 1 + dy;               // real image row within patch
            const bool vrow = has && (yy >= 0) && (yy <= 8);
            #pragma unroll
            for (int j = 0; j < 27; ++j) rf[dy][j] = 0.f;
            if (vrow) {
                #pragma unroll
                for (int c = 0; c < 3; ++c) {
                    const float* rp = images + (size_t)base + c * HW + yy * 384;
                    #pragma unroll
                    for (int x = 0; x < 9; ++x) rf[dy][c * 9 + x] = rp[x];
                }
            }
        }
    }

    const int oc0 = w * 32 + n16;
    const int oc1 = oc0 + 16;

    // B prefetch for channel 0 (two alternating named register sets, static idx)
    uint4 PBa[3][2], PBb[3][2];
    load_B<USEWS>(W2b, W2, 0, oc0, oc1, g4, PBa);

    f32x4 acc[2][2];
    #pragma unroll
    for (int mt = 0; mt < 2; ++mt)
        #pragma unroll
        for (int nt = 0; nt < 2; ++nt) acc[mt][nt] = (f32x4){0.f, 0.f, 0.f, 0.f};

    const u32 hoff = (u32)(p0 * (HST / 2) + y0 * 5);  // u32 index of this task's H row

    #pragma unroll 1
    for (int o = 0; o < 16; ++o) {
        const int c0 = o * 4;
        const int bsel = (o & 1) * 4;

        // ---- phase 1: conv1 for channels c0..c0+3 into Hl[bsel..bsel+3] ----
        #pragma unroll 1
        for (int i = 0; i < 4; ++i) {
            const int c = c0 + i;
            const float* W1c = W1 + (size_t)c * 27;
            const float bias = b1[c];
            float a[9];
            #pragma unroll
            for (int x = 0; x < 9; ++x) a[x] = bias;
            #pragma unroll
            for (int dy = 0; dy < 3; ++dy) {
                #pragma unroll
                for (int cc = 0; cc < 3; ++cc) {
                    const float* rr = rf[dy] + cc * 9;
                    const int wi = cc * 9 + dy * 3;
                    const float w0 = W1c[wi], w1 = W1c[wi + 1], w2 = W1c[wi + 2];
                    #pragma unroll
                    for (int xo = 0; xo < 9; ++xo) {
                        a[xo] = fmaf(rr[xo], w1, a[xo]);
                        if (xo >= 1) a[xo] = fmaf(rr[xo - 1], w0, a[xo]);
                        if (xo <= 7) a[xo] = fmaf(rr[xo + 1], w2, a[xo]);
                    }
                }
            }
            #pragma unroll
            for (int xo = 0; xo < 9; ++xo) a[xo] = fmaxf(a[xo], 0.f);   // ReLU
            // pack 9 values + zero pad -> 5 u32 (RNE, bit-identical to f2bf)
            u32 hw0 = cvtpk(a[0], a[1]);
            u32 hw1 = cvtpk(a[2], a[3]);
            u32 hw2 = cvtpk(a[4], a[5]);
            u32 hw3 = cvtpk(a[6], a[7]);
            u32 hw4 = cvtpk(a[8], 0.f);
            if (has) {
                u32* d = (u32*)(&Hl[bsel + i][0]) + hoff;
                d[0] = hw0; d[1] = hw1; d[2] = hw2; d[3] = hw3; d[4] = hw4;
            }
        }

        __syncthreads();   // H(octet o) visible; all waves past MFMA(o-1)

        // ---- phase 2: 4 channels of MFMA, B ping-pong prefetched in registers ----
        load_B<USEWS>(W2b, W2, c0 + 1, oc0, oc1, g4, PBb);
        mfma_ch(&Hl[bsel + 0][0], n16, g4, PBa, acc);
        load_B<USEWS>(W2b, W2, c0 + 2, oc0, oc1, g4, PBa);
        mfma_ch(&Hl[bsel + 1][0], n16, g4, PBb, acc);
        load_B<USEWS>(W2b, W2, c0 + 3, oc0, oc1, g4, PBb);
        mfma_ch(&Hl[bsel + 2][0], n16, g4, PBa, acc);
        load_B<USEWS>(W2b, W2, o < 15 ? c0 + 4 : 0, oc0, oc1, g4, PBa);  // next octet
        mfma_ch(&Hl[bsel + 3][0], n16, g4, PBb, acc);
        // no barrier here: next conv1 writes the OTHER buffer quad
    }

    // ---- epilogue: + b2, write fp32 (B,N,128), guard tail rows ----
    const float bias0 = b2[oc0];
    const float bias1 = b2[oc1];
    #pragma unroll
    for (int mt = 0; mt < 2; ++mt) {
        #pragma unroll
        for (int r = 0; r < 4; ++r) {
            int p = mt * 16 + g4 * 4 + r;
            int gp = blk * PP + p;
            if (p < PP && gp < NPATCH) {
                size_t rowo = (size_t)gp * 128;
                out[rowo + oc0] = acc[mt][0][r] + bias0;
                out[rowo + oc1] = acc[mt][1][r] + bias1;
            }
        }
    }
}

extern "C" void kernel_launch(void* const* d_in, const int* in_sizes, int n_in,
                              void* d_out, int out_size, void* d_ws, size_t ws_size,
                              hipStream_t stream)
{
    const float* images = (const float*)d_in[0];
    const float* coords = (const float*)d_in[1];
    const int*   t_src  = (const int*)d_in[2];
    const float* W1     = (const float*)d_in[3];
    const float* b1     = (const float*)d_in[4];
    const float* W2     = (const float*)d_in[5];
    const float* b2     = (const float*)d_in[6];
    float* out = (float*)d_out;
    u16* W2b = (u16*)d_ws;

    const int grid = (NPATCH + PP - 1) / PP;   // 1171
    const bool usews = ws_size >= (size_t)W2B_ELEMS * sizeof(u16);   // 1.70 MB

    if (usews) {
        hipLaunchKernelGGL(w2_prep, dim3((W2B_ELEMS + 255) / 256), dim3(256), 0, stream,
                           W2, W2b);
        hipLaunchKernelGGL(patch_embed<true>, dim3(grid), dim3(NTHR), 0, stream,
                           images, coords, t_src, W1, b1, W2, W2b, b2, out);
    } else {
        hipLaunchKernelGGL(patch_embed<false>, dim3(grid), dim3(NTHR), 0, stream,
                           images, coords, t_src, W1, b1, W2, W2b, b2, out);
    }
}